// Round 23
// baseline (724.594 us; speedup 1.0000x reference)
//
#include <hip/hip_runtime.h>
#include <hip/hip_bf16.h>

// 3-layer stacked LSTM forward (eval). Round 23 = exact revert to r20 (723us,
// verified passing, absmax bit-exact 0.001953125). The r21/r22 DPP gate-
// exchange experiment is abandoned: r22 failed absmax at 1.17e-2 with a
// suspected DPP-after-inline-asm hazard that is not fixable at HIP level.
// r20 is the structural plateau:
//  - scan1: r13 8-wave uniform-b128 scan, weights VGPR-resident (in-loop pin +
//    waves_per_eu), ~90% of its DS-pipe floor. Design space bracketed:
//    MFMA scans (r7-r11), 2/4-wave topologies (r14/r15), readlane (r16),
//    hybrid (r17), DPP (r21/r22) -- all worse or incorrect.
//  - scan23: L2 scan + wave-4-fused L3 (kills gemm_xg3b/scan3/h2 round-trip).
//  - gemm_mfma: r4-verified bf16 MFMA 128x128 with XOR-swizzled LDS.
//  - NCH=2 chunking, xg1/xg2 aliased, 2-launch prep.
// T=512, B=256, IN=97(pad128), H1=128, H2=64, H3=1.

#define T_TOT 512
#define BB    256
#define CH    256
#define NCH   2

typedef __attribute__((ext_vector_type(8))) short  short8v;   // 8 bf16
typedef __attribute__((ext_vector_type(4))) float  float4v;   // MFMA acc

// acc += w.lo*h.lo + w.hi*h.hi (VOP3P, verified r5+)
#define DOT2BF(acc, wu, hu) \
    asm("v_dot2_f32_bf16 %0, %1, %2, %0" : "+v"(acc) : "v"(wu), "v"(hu))

__device__ __forceinline__ float sigm(float x) {
    float e = __expf(-x);
    return __builtin_amdgcn_rcpf(1.0f + e);
}
__device__ __forceinline__ float tanh_(float x) {
    float e = __expf(2.0f * x);
    return 1.0f - 2.0f * __builtin_amdgcn_rcpf(1.0f + e);
}
__device__ __forceinline__ unsigned short f2bf(float x) {
    __hip_bfloat16 b = __float2bfloat16(x);
    return __builtin_bit_cast(unsigned short, b);
}
__device__ __forceinline__ float readlane_f(float v, int l) {
    unsigned int u = __builtin_amdgcn_readlane(__builtin_bit_cast(unsigned int, v), l);
    return __builtin_bit_cast(float, u);
}

// ---------------------------------------------------------------------------
// Big input conversion (x -> bf16 padded).
// ---------------------------------------------------------------------------
__global__ __launch_bounds__(256) void cvt_pad_x(
    const float* __restrict__ in, __hip_bfloat16* __restrict__ out)
{
    int total = T_TOT * BB * 128;
    for (int idx = blockIdx.x * 256 + threadIdx.x; idx < total; idx += gridDim.x * 256) {
        int r = idx >> 7, c = idx & 127;
        float v = (c < 97) ? in[(size_t)r * 97 + c] : 0.0f;
        out[idx] = __float2bfloat16(v);
    }
}

// ---------------------------------------------------------------------------
// prep_small: all weight/bias conversions in one kernel.
// ---------------------------------------------------------------------------
__global__ __launch_bounds__(256) void prep_small(
    const float* __restrict__ Wih1, const float* __restrict__ Whh1,
    const float* __restrict__ Wih2, const float* __restrict__ Whh2,
    const float* __restrict__ bih1, const float* __restrict__ bhh1,
    const float* __restrict__ bih2, const float* __restrict__ bhh2,
    __hip_bfloat16* __restrict__ wb1, __hip_bfloat16* __restrict__ whb1,
    __hip_bfloat16* __restrict__ wb2, __hip_bfloat16* __restrict__ whb2,
    float* __restrict__ bias1, float* __restrict__ bias2)
{
    int idx = blockIdx.x * 256 + threadIdx.x;
    if (idx < 65536) {
        int r = idx >> 7, c = idx & 127;
        float v = (c < 97) ? Wih1[(size_t)r * 97 + c] : 0.0f;
        wb1[idx] = __float2bfloat16(v);
    } else if (idx < 131072) {
        int i = idx - 65536;
        whb1[i] = __float2bfloat16(Whh1[i]);
    } else if (idx < 163840) {
        int i = idx - 131072;
        wb2[i] = __float2bfloat16(Wih2[i]);
    } else if (idx < 180224) {
        int i = idx - 163840;
        whb2[i] = __float2bfloat16(Whh2[i]);
    } else if (idx < 180736) {
        int i = idx - 180224;
        bias1[i] = bih1[i] + bhh1[i];
    } else if (idx < 180992) {
        int i = idx - 180736;
        bias2[i] = bih2[i] + bhh2[i];
    }
}

// ---------------------------------------------------------------------------
// bf16 MFMA GEMM (r4, verified): C[M,N] = A[M,128] * W[N,128]^T + bias
// ---------------------------------------------------------------------------
__global__ __launch_bounds__(256) void gemm_mfma(
    const __hip_bfloat16* __restrict__ A,
    const __hip_bfloat16* __restrict__ W,
    const float* __restrict__ bias,
    float* __restrict__ C, int N)
{
    __shared__ __hip_bfloat16 At[128 * 128];   // 32 KB

    const int tid  = threadIdx.x;
    const int lane = tid & 63;
    const int wid  = tid >> 6;
    const int m0   = blockIdx.x * 128;
    const int n0   = blockIdx.y * 128;
    const int wr   = wid >> 1;
    const int wc   = wid & 1;

    short8v bfrag[4][4];  // [nf][kf]
    {
        const char* Wg = (const char*)W;
#pragma unroll
        for (int nf = 0; nf < 4; ++nf) {
            int row = n0 + wc * 64 + nf * 16 + (lane & 15);
#pragma unroll
            for (int kf = 0; kf < 4; ++kf) {
                int colb = (kf * 32 + (lane >> 4) * 8) * 2;
                bfrag[nf][kf] = *(const short8v*)(Wg + (size_t)row * 256 + colb);
            }
        }
    }
    {
        const char* Ag = (const char*)(A + (size_t)m0 * 128);
        char* As = (char*)At;
#pragma unroll
        for (int r2 = 0; r2 < 8; ++r2) {
            int off = r2 * 4096 + tid * 16;
            int row = off >> 8;
            int bir = off & 255;
            short8v v = *(const short8v*)(Ag + (size_t)row * 256 + bir);
            int sw = bir ^ ((row & 7) << 4);
            *(short8v*)(As + row * 256 + sw) = v;
        }
    }
    __syncthreads();

    float4v acc[4][4] = {};
#pragma unroll
    for (int kf = 0; kf < 4; ++kf) {
        short8v af[4];
#pragma unroll
        for (int mf = 0; mf < 4; ++mf) {
            int row   = wr * 64 + mf * 16 + (lane & 15);
            int kbyte = kf * 64 + (lane >> 4) * 16;
            int sw    = kbyte ^ ((row & 7) << 4);
            af[mf] = *(const short8v*)((const char*)At + row * 256 + sw);
        }
#pragma unroll
        for (int mf = 0; mf < 4; ++mf)
#pragma unroll
            for (int nf = 0; nf < 4; ++nf)
                acc[mf][nf] = __builtin_amdgcn_mfma_f32_16x16x32_bf16(
                    af[mf], bfrag[nf][kf], acc[mf][nf], 0, 0, 0);
    }

#pragma unroll
    for (int nf = 0; nf < 4; ++nf) {
        int col = n0 + wc * 64 + nf * 16 + (lane & 15);
        float bv = bias[col];
#pragma unroll
        for (int mf = 0; mf < 4; ++mf) {
            int rbase = m0 + wr * 64 + mf * 16 + (lane >> 4) * 4;
#pragma unroll
            for (int r = 0; r < 4; ++r)
                C[(size_t)(rbase + r) * N + col] = acc[mf][nf][r] + bv;
        }
    }
}

// ---------------------------------------------------------------------------
// scan1 (H=128): r13 structure (DS-pipe-bound local optimum).
// ---------------------------------------------------------------------------
__global__ __launch_bounds__(512)
__attribute__((amdgpu_waves_per_eu(2, 2)))
void lstm_scan1(
    const float* __restrict__ xg,        // [Tc, BB, 512] f32, bias included
    const unsigned int* __restrict__ Wp, // [512 rows][64 uint] bf16-pairs
    __hip_bfloat16* __restrict__ hout,   // [Tc, BB, 128]
    float* __restrict__ hstate, float* __restrict__ cstate,
    int Tc, int first)
{
    const int n   = threadIdx.x;     // gate-row 0..511
    const int row = blockIdx.x;
    __shared__ unsigned int hbuf[2][64];   // 128 bf16, double-buffered
    __shared__ float g_lds[512];

    uint4 w[16];   // 64 VGPR of weights, static-indexed
    {
        const uint4* wr_ = (const uint4*)(Wp + (size_t)n * 64);
#pragma unroll
        for (int j = 0; j < 16; ++j) w[j] = wr_[j];
    }

    float c = 0.0f, hf = 0.0f;
    if (n < 128) {
        c  = first ? 0.0f : cstate[row * 128 + n];
        hf = first ? 0.0f : hstate[row * 128 + n];
        ((unsigned short*)hbuf[0])[n] = f2bf(hf);
    }
    __syncthreads();

    const float* px = xg + (size_t)row * 512 + n;
    float xc = px[0];
    float xn = (Tc > 1) ? px[(size_t)BB * 512] : 0.0f;

    int cur = 0;
    for (int t = 0; t < Tc; ++t) {
        // In-loop pin (r13-verified): weights loop-carried, un-reloadable.
#pragma unroll
        for (int j = 0; j < 16; ++j)
            asm volatile("" : "+v"(w[j].x), "+v"(w[j].y), "+v"(w[j].z), "+v"(w[j].w));

        float a = xc;
        xc = xn;
        if (t + 2 < Tc) xn = px[(size_t)(t + 2) * BB * 512];

        const uint4* hb = (const uint4*)hbuf[cur];   // wave-uniform (broadcast)
#pragma unroll
        for (int j = 0; j < 16; ++j) {
            uint4 hv = hb[j];
            DOT2BF(a, w[j].x, hv.x); DOT2BF(a, w[j].y, hv.y);
            DOT2BF(a, w[j].z, hv.z); DOT2BF(a, w[j].w, hv.w);
        }
        g_lds[n] = a;
        __syncthreads();

        if (n < 128) {
            float i_ = sigm(g_lds[n]);
            float f_ = sigm(g_lds[n + 128]);
            float g_ = tanh_(g_lds[n + 256]);
            float o_ = sigm(g_lds[n + 384]);
            c  = fmaf(f_, c, i_ * g_);
            hf = o_ * tanh_(c);
            unsigned short hb16 = f2bf(hf);
            ((unsigned short*)hbuf[cur ^ 1])[n] = hb16;
            ((unsigned short*)hout)[((size_t)t * BB + row) * 128 + n] = hb16;
        }
        cur ^= 1;
        __syncthreads();
    }
    if (n < 128) {
        cstate[row * 128 + n] = c;
        hstate[row * 128 + n] = hf;
    }
}

// ---------------------------------------------------------------------------
// scan23: layer-2 scan (waves 0-3) + layer-3 fused on wave 4 (r19-verified).
// ---------------------------------------------------------------------------
__global__ __launch_bounds__(320)
__attribute__((amdgpu_waves_per_eu(1, 1)))
void lstm_scan23(
    const float* __restrict__ xg,        // [Tc, BB, 256] f32, bias included
    const unsigned int* __restrict__ Wp, // [256 rows][32 uint] bf16-pairs
    float* __restrict__ hstate, float* __restrict__ cstate,   // L2 state
    const float* __restrict__ Wx3,       // [4,64] f32 (raw Wih3)
    const float* __restrict__ Wh3,       // [4,1]  f32 (raw Whh3)
    const float* __restrict__ bih3, const float* __restrict__ bhh3,
    float* __restrict__ st3h, float* __restrict__ st3c,       // [B] L3 state
    float* __restrict__ out,             // [T, BB]
    int Tc, int first, int tbase)
{
    const int tid = threadIdx.x;
    const int row = blockIdx.x;
    __shared__ unsigned int hbuf[2][32];   // h2 bf16 pairs, dbuf
    __shared__ float g_lds[256];
    __shared__ float h2f[2][64];           // h2 f32 ring for L3

    if (tid < 256) {
        // ================= waves 0-3: layer-2 scan =================
        const int n = tid;    // gate-row 0..255

        uint4 w[8];
        {
            const uint4* wr_ = (const uint4*)(Wp + (size_t)n * 32);
#pragma unroll
            for (int j = 0; j < 8; ++j) w[j] = wr_[j];
        }

        float c = 0.0f, hf = 0.0f;
        if (n < 64) {
            c  = first ? 0.0f : cstate[row * 64 + n];
            hf = first ? 0.0f : hstate[row * 64 + n];
            ((unsigned short*)hbuf[0])[n] = f2bf(hf);
            h2f[0][n] = hf;
        }
        __syncthreads();

        const float* px = xg + (size_t)row * 256 + n;
        float xc = px[0];
        float xn = (Tc > 1) ? px[(size_t)BB * 256] : 0.0f;

        int cur = 0;
        for (int t = 0; t < Tc; ++t) {
#pragma unroll
            for (int j = 0; j < 8; ++j)
                asm volatile("" : "+v"(w[j].x), "+v"(w[j].y), "+v"(w[j].z), "+v"(w[j].w));

            float a = xc;
            xc = xn;
            if (t + 2 < Tc) xn = px[(size_t)(t + 2) * BB * 256];

            const uint4* hb = (const uint4*)hbuf[cur];
#pragma unroll
            for (int j = 0; j < 8; ++j) {
                uint4 hv = hb[j];
                DOT2BF(a, w[j].x, hv.x); DOT2BF(a, w[j].y, hv.y);
                DOT2BF(a, w[j].z, hv.z); DOT2BF(a, w[j].w, hv.w);
            }
            g_lds[n] = a;
            __syncthreads();

            if (n < 64) {
                float i_ = sigm(g_lds[n]);
                float f_ = sigm(g_lds[n + 64]);
                float g_ = tanh_(g_lds[n + 128]);
                float o_ = sigm(g_lds[n + 192]);
                c  = fmaf(f_, c, i_ * g_);
                hf = o_ * tanh_(c);
                ((unsigned short*)hbuf[cur ^ 1])[n] = f2bf(hf);
                h2f[cur ^ 1][n] = hf;
            }
            cur ^= 1;
            __syncthreads();
        }
        if (n < 64) {
            cstate[row * 64 + n] = c;
            hstate[row * 64 + n] = hf;
        }
    } else {
        // ================= wave 4: layer 3 (H=1) =================
        const int lane = tid - 256;      // 0..63
        const int g    = lane >> 4;      // gate 0..3
        const int i    = lane & 15;      // element group 0..15

        float4 w3 = *(const float4*)(Wx3 + g * 64 + 4 * i);
        float b3[4], wh3[4];
#pragma unroll
        for (int k = 0; k < 4; ++k) { b3[k] = bih3[k] + bhh3[k]; wh3[k] = Wh3[k]; }
        float h3 = first ? 0.0f : st3h[row];
        float c3 = first ? 0.0f : st3c[row];

        __syncthreads();   // matches scan-side init barrier

        int cur = 0;
        for (int t = 0; t < Tc; ++t) {
            if (t >= 1) {
                float4 hv = *(const float4*)(&h2f[cur][4 * i]);
                float p = hv.x * w3.x;
                p = fmaf(hv.y, w3.y, p);
                p = fmaf(hv.z, w3.z, p);
                p = fmaf(hv.w, w3.w, p);
                p += __shfl_xor(p, 1);
                p += __shfl_xor(p, 2);
                p += __shfl_xor(p, 4);
                p += __shfl_xor(p, 8);
                float s0 = readlane_f(p, 0);
                float s1 = readlane_f(p, 16);
                float s2 = readlane_f(p, 32);
                float s3 = readlane_f(p, 48);
                float gi  = fmaf(h3, wh3[0], s0 + b3[0]);
                float gf  = fmaf(h3, wh3[1], s1 + b3[1]);
                float gg_ = fmaf(h3, wh3[2], s2 + b3[2]);
                float go  = fmaf(h3, wh3[3], s3 + b3[3]);
                float i_ = sigm(gi);
                float f_ = sigm(gf);
                float g_ = tanh_(gg_);
                float o_ = sigm(go);
                c3 = fmaf(f_, c3, i_ * g_);
                h3 = o_ * tanh_(c3);
                if (lane == 0)
                    out[(size_t)(tbase + t - 1) * BB + row] = h3;
            }
            __syncthreads();   // barrier 1
            __syncthreads();   // barrier 2
            cur ^= 1;
        }
        // tail: out[tbase+Tc-1] from h2f[cur] (last step's h2)
        {
            float4 hv = *(const float4*)(&h2f[cur][4 * i]);
            float p = hv.x * w3.x;
            p = fmaf(hv.y, w3.y, p);
            p = fmaf(hv.z, w3.z, p);
            p = fmaf(hv.w, w3.w, p);
            p += __shfl_xor(p, 1);
            p += __shfl_xor(p, 2);
            p += __shfl_xor(p, 4);
            p += __shfl_xor(p, 8);
            float s0 = readlane_f(p, 0);
            float s1 = readlane_f(p, 16);
            float s2 = readlane_f(p, 32);
            float s3 = readlane_f(p, 48);
            float gi  = fmaf(h3, wh3[0], s0 + b3[0]);
            float gf  = fmaf(h3, wh3[1], s1 + b3[1]);
            float gg_ = fmaf(h3, wh3[2], s2 + b3[2]);
            float go  = fmaf(h3, wh3[3], s3 + b3[3]);
            float i_ = sigm(gi);
            float f_ = sigm(gf);
            float g_ = tanh_(gg_);
            float o_ = sigm(go);
            c3 = fmaf(f_, c3, i_ * g_);
            h3 = o_ * tanh_(c3);
            if (lane == 0) {
                out[(size_t)(tbase + Tc - 1) * BB + row] = h3;
                st3h[row] = h3;
                st3c[row] = c3;
            }
        }
    }
}

// ---------------------------------------------------------------------------
extern "C" void kernel_launch(void* const* d_in, const int* in_sizes, int n_in,
                              void* d_out, int out_size, void* d_ws, size_t ws_size,
                              hipStream_t stream) {
    const float* x    = (const float*)d_in[0];
    const float* Wih1 = (const float*)d_in[1];
    const float* Whh1 = (const float*)d_in[2];
    const float* bih1 = (const float*)d_in[3];
    const float* bhh1 = (const float*)d_in[4];
    const float* Wih2 = (const float*)d_in[5];
    const float* Whh2 = (const float*)d_in[6];
    const float* bih2 = (const float*)d_in[7];
    const float* bhh2 = (const float*)d_in[8];
    const float* Wih3 = (const float*)d_in[9];
    const float* Whh3 = (const float*)d_in[10];
    const float* bih3 = (const float*)d_in[11];
    const float* bhh3 = (const float*)d_in[12];
    float* out = (float*)d_out;

    char* ws = (char*)d_ws;
    // Workspace ~202 MB. xg2 aliases the xg1 region (phases sequential).
    float*          xg1   = (float*)(ws + 0);                   // [256,B,512] f32 = 134,217,728
    float*          xg2   = (float*)(ws + 0);                   // alias (P2 only)
    __hip_bfloat16* xb    = (__hip_bfloat16*)(ws + 134217728);  // 33,554,432
    __hip_bfloat16* h1b   = (__hip_bfloat16*)(ws + 167772160);  // 33,554,432
    __hip_bfloat16* wb1   = (__hip_bfloat16*)(ws + 201326592);  //   131,072
    __hip_bfloat16* whb1  = (__hip_bfloat16*)(ws + 201457664);  //   131,072
    __hip_bfloat16* wb2   = (__hip_bfloat16*)(ws + 201588736);  //    65,536
    __hip_bfloat16* whb2  = (__hip_bfloat16*)(ws + 201654272);  //    32,768
    float*          bias1 = (float*)(ws + 201687040);           //     2,048
    float*          bias2 = (float*)(ws + 201689088);           //     1,024
    float*          st1h  = (float*)(ws + 201690112);           //   131,072
    float*          st1c  = (float*)(ws + 201821184);           //   131,072
    float*          st2h  = (float*)(ws + 201952256);           //    65,536
    float*          st2c  = (float*)(ws + 202017792);           //    65,536
    float*          st3h  = (float*)(ws + 202083328);           //     1,024
    float*          st3c  = (float*)(ws + 202084352);           //     1,024

    // ---- P0: conversions / bias prep (2 launches) ----
    cvt_pad_x<<<4096, 256, 0, stream>>>(x, xb);
    prep_small<<<708, 256, 0, stream>>>(
        Wih1, Whh1, Wih2, Whh2, bih1, bhh1, bih2, bhh2,
        wb1, whb1, wb2, whb2, bias1, bias2);

    // ---- P1: Layer 1 (2 chunks of 256 steps) ----
    for (int c0 = 0; c0 < NCH; ++c0) {
        gemm_mfma<<<dim3(CH * BB / 128, 512 / 128), 256, 0, stream>>>(
            xb + (size_t)c0 * CH * BB * 128, wb1, bias1, xg1, 512);
        lstm_scan1<<<BB, 512, 0, stream>>>(
            xg1, (const unsigned int*)whb1,
            h1b + (size_t)c0 * CH * BB * 128, st1h, st1c, CH, c0 == 0);
    }
    // ---- P2: Layers 2+3 (2 chunks; L3 fused on wave 4) ----
    for (int c0 = 0; c0 < NCH; ++c0) {
        gemm_mfma<<<dim3(CH * BB / 128, 256 / 128), 256, 0, stream>>>(
            h1b + (size_t)c0 * CH * BB * 128, wb2, bias2, xg2, 256);
        lstm_scan23<<<BB, 320, 0, stream>>>(
            xg2, (const unsigned int*)whb2, st2h, st2c,
            Wih3, Whh3, bih3, bhh3, st3h, st3c, out,
            CH, c0 == 0, c0 * CH);
    }
}